// Round 11
// baseline (296.874 us; speedup 1.0000x reference)
//
#include <hip/hip_runtime.h>
#include <hip/hip_bf16.h>

constexpr int Bb = 2, Hh = 32, Ss = 1024, Dd = 64;
constexpr int NBH = Bb * Hh;     // 64

// M-slot indirection for fallback paths.
__device__ __forceinline__ float* m_slot(float* A, float* B, int nplo,
                                         int bh, int p, int np) {
    return (p < nplo) ? A + ((size_t)bh * nplo + p) * 4096
                      : B + ((size_t)bh * (np - nplo) + (p - nplo)) * 4096;
}

// ---------------------------------------------------------------------------
// Phase 1: BARRIER-FREE per-step scan. One 128-thread block per (bh,p):
//   wave 0 (G): h[64] zero-init, input k v^T; per-step o_t = q^T h -> out
//   wave 1 (M): h[64] identity-init, homogeneous; per-step z_t = q^T M -> zbuf
// Full 64-row state in ONE wave's VGPRs; a^T h, update, q^T h all in-register.
// LDS staging per CH-step chunk (2 barriers per chunk), fully unrolled steps.
// ---------------------------------------------------------------------------
template<int SEG, int CH>
__global__ __launch_bounds__(128, 4) void scan_wave(
    const float* __restrict__ qp, const float* __restrict__ kp,
    const float* __restrict__ vp, const float* __restrict__ ap,
    const float* __restrict__ bp, const float* __restrict__ gkp,
    float* __restrict__ Gbuf, float* __restrict__ Mbuf,
    float* __restrict__ zbuf, float* __restrict__ out)
{
    constexpr int NP = Ss / SEG;
    const int tid  = (int)threadIdx.x;
    const int lane = tid & 63;
    const int wv   = __builtin_amdgcn_readfirstlane(tid >> 6);   // 0=G, 1=M
    const int bid  = (int)blockIdx.x;            // bh*NP + p
    const int p    = bid & (NP - 1);
    const int bh   = bid / NP;
    const int b    = bh >> 5, hh = bh & (Hh - 1);
    const size_t segbase = (size_t)bid * (SEG * Dd);

    __shared__ float la[CH * 64], lb[CH * 64], lw_[CH * 64];
    __shared__ float lq[CH * 64], lk[CH * 64], lv[CH * 64];

    float h[64];
#pragma unroll
    for (int j = 0; j < 64; ++j) h[j] = wv ? ((j == lane) ? 1.f : 0.f) : 0.f;

    for (int c0 = 0; c0 < SEG; c0 += CH) {
        __syncthreads();                          // prior chunk LDS reads done
        {
            const size_t gb = segbase + (size_t)c0 * 64;
            const float4* a4 = (const float4*)(ap + gb);
            const float4* b4 = (const float4*)(bp + gb);
            const float4* g4 = (const float4*)(gkp + gb);
            const float4* q4 = (const float4*)(qp + gb);
            const float4* k4 = (const float4*)(kp + gb);
            const float4* v4 = (const float4*)(vp + gb);
#pragma unroll
            for (int i = tid; i < CH * 16; i += 128) {
                ((float4*)la)[i] = a4[i];
                ((float4*)lb)[i] = b4[i];
                float4 g = g4[i], e;
                e.x = __expf(g.x); e.y = __expf(g.y);
                e.z = __expf(g.z); e.w = __expf(g.w);
                ((float4*)lw_)[i] = e;
                ((float4*)lq)[i] = q4[i];
                ((float4*)lk)[i] = k4[i];
                ((float4*)lv)[i] = v4[i];
            }
        }
        __syncthreads();                          // staging visible

#pragma unroll
        for (int tl = 0; tl < CH; ++tl) {
            const int t = c0 + tl;
            // ---- a^T h : 64 in-register FMAs (broadcast b128 reads of a)
            const float4* ar = (const float4*)(la + tl * 64);
            float s0 = 0.f, s1 = 0.f, s2 = 0.f, s3 = 0.f;
#pragma unroll
            for (int jj = 0; jj < 16; ++jj) {
                const float4 a4 = ar[jj];
                s0 = fmaf(a4.x, h[4*jj+0], s0);
                s1 = fmaf(a4.y, h[4*jj+1], s1);
                s2 = fmaf(a4.z, h[4*jj+2], s2);
                s3 = fmaf(a4.w, h[4*jj+3], s3);
            }
            const float ah = (s0 + s1) + (s2 + s3);

            // ---- state update + q^T h (all in-register)
            const float4* br = (const float4*)(lb  + tl * 64);
            const float4* wr = (const float4*)(lw_ + tl * 64);
            const float4* qr = (const float4*)(lq  + tl * 64);
            float o0 = 0.f, o1 = 0.f, o2 = 0.f, o3 = 0.f;
            if (wv == 0) {                        // G wave
                const float u = lv[tl * 64 + lane];
                const float4* kr = (const float4*)(lk + tl * 64);
#pragma unroll
                for (int jj = 0; jj < 16; ++jj) {
                    const float4 b4 = br[jj], k4 = kr[jj], w4 = wr[jj], q4 = qr[jj];
                    h[4*jj+0] = fmaf(w4.x, h[4*jj+0], fmaf(b4.x, ah, k4.x * u));
                    o0 = fmaf(q4.x, h[4*jj+0], o0);
                    h[4*jj+1] = fmaf(w4.y, h[4*jj+1], fmaf(b4.y, ah, k4.y * u));
                    o1 = fmaf(q4.y, h[4*jj+1], o1);
                    h[4*jj+2] = fmaf(w4.z, h[4*jj+2], fmaf(b4.z, ah, k4.z * u));
                    o2 = fmaf(q4.z, h[4*jj+2], o2);
                    h[4*jj+3] = fmaf(w4.w, h[4*jj+3], fmaf(b4.w, ah, k4.w * u));
                    o3 = fmaf(q4.w, h[4*jj+3], o3);
                }
                const int s = p * SEG + t;
                out[(((size_t)b * Ss + s) * Hh + hh) * Dd + lane] =
                    (o0 + o1) + (o2 + o3);
            } else {                              // M wave
#pragma unroll
                for (int jj = 0; jj < 16; ++jj) {
                    const float4 b4 = br[jj], w4 = wr[jj], q4 = qr[jj];
                    h[4*jj+0] = fmaf(w4.x, h[4*jj+0], b4.x * ah);
                    o0 = fmaf(q4.x, h[4*jj+0], o0);
                    h[4*jj+1] = fmaf(w4.y, h[4*jj+1], b4.y * ah);
                    o1 = fmaf(q4.y, h[4*jj+1], o1);
                    h[4*jj+2] = fmaf(w4.z, h[4*jj+2], b4.z * ah);
                    o2 = fmaf(q4.z, h[4*jj+2], o2);
                    h[4*jj+3] = fmaf(w4.w, h[4*jj+3], b4.w * ah);
                    o3 = fmaf(q4.w, h[4*jj+3], o3);
                }
                zbuf[segbase + (size_t)t * 64 + lane] = (o0 + o1) + (o2 + o3);
            }
        }
    }

    float* dst = (wv == 0) ? Gbuf + (size_t)bid * 4096
                           : Mbuf + (size_t)bid * 4096;
#pragma unroll
    for (int j = 0; j < 64; ++j) dst[j * 64 + lane] = h[j];
}

// ---------------------------------------------------------------------------
// Phase 2 (proven r8-r10): SW_p = M_p * SW_{p-1} + G_p.
// XCD-aware: bh = bid & 63 -> 4 col-blocks of a bh land on the same XCD.
// ---------------------------------------------------------------------------
template<int NP>
__global__ __launch_bounds__(256) void combine(
    const float* MbufA, const float* MbufB, int nplo, float* __restrict__ Gbuf)
{
    const int bh  = (int)blockIdx.x & (NBH - 1);
    const int cb  = (int)blockIdx.x >> 6;
    const int c0  = cb * 16;
    const int tid = (int)threadIdx.x;
    const int cl  = tid & 15;
    const int c   = c0 + cl;
    const int rg  = tid >> 4;            // 0..15
    const int r0  = rg * 4;
    const int xorv = (rg & 1) << 2;

    __shared__ float4 Ml[2][1024];
    __shared__ __align__(16) float swT[16][68];

    {
        const float* G0 = Gbuf + (size_t)bh * NP * 4096;
        for (int i = tid; i < 1024; i += 256)
            swT[i & 15][i >> 4] = G0[(i >> 4) * 64 + c0 + (i & 15)];
    }

    float4 mreg[4];
    if (NP > 1) {
        const float4* Mp = (const float4*)m_slot((float*)MbufA, (float*)MbufB,
                                                 nplo, bh, 1, NP);
#pragma unroll
        for (int j = 0; j < 4; ++j) mreg[j] = Mp[j * 256 + tid];
    }
    __syncthreads();
#pragma unroll
    for (int j = 0; j < 4; ++j) {
        const int f = j * 256 + tid;
        Ml[0][f ^ ((f >> 4) & 4)] = mreg[j];
    }
    if (NP > 2) {
        const float4* Mp = (const float4*)m_slot((float*)MbufA, (float*)MbufB,
                                                 nplo, bh, 2, NP);
#pragma unroll
        for (int j = 0; j < 4; ++j) mreg[j] = Mp[j * 256 + tid];
    }
    __syncthreads();

    for (int p = 1; p < NP; ++p) {
        const int par = (p - 1) & 1;
        float* Gp = Gbuf + ((size_t)bh * NP + p) * 4096;

        float gacc[4];
#pragma unroll
        for (int r = 0; r < 4; ++r) gacc[r] = Gp[(r0 + r) * 64 + c];

        float accA[4] = {0.f, 0.f, 0.f, 0.f};
        float accB[4] = {0.f, 0.f, 0.f, 0.f};
        const float4* swr = (const float4*)&swT[cl][0];
#pragma unroll
        for (int m4 = 0; m4 < 16; ++m4) {
            const float4 s = swr[m4];
            const int ms = m4 ^ xorv;
#pragma unroll
            for (int r = 0; r < 4; ++r) {
                const float4 m = Ml[par][(r0 + r) * 16 + ms];
                accA[r] = fmaf(m.x, s.x, fmaf(m.y, s.y, accA[r]));
                accB[r] = fmaf(m.z, s.z, fmaf(m.w, s.w, accB[r]));
            }
        }
        __syncthreads();

#pragma unroll
        for (int r = 0; r < 4; ++r) {
            const float val = accA[r] + accB[r] + gacc[r];
            swT[cl][r0 + r] = val;
            Gp[(r0 + r) * 64 + c] = val;
        }
        if (p + 1 < NP) {
#pragma unroll
            for (int j = 0; j < 4; ++j) {
                const int f = j * 256 + tid;
                Ml[par ^ 1][f ^ ((f >> 4) & 4)] = mreg[j];
            }
        }
        if (p + 2 < NP) {
            const float4* Mp = (const float4*)m_slot((float*)MbufA, (float*)MbufB,
                                                     nplo, bh, p + 2, NP);
#pragma unroll
            for (int j = 0; j < 4; ++j) mreg[j] = Mp[j * 256 + tid];
        }
        __syncthreads();
    }
}

// ---------------------------------------------------------------------------
// Phase 3 (proven r8-r10): out[t] += z_t^T SW_{p-1}.
// ---------------------------------------------------------------------------
template<int SEG>
__global__ __launch_bounds__(256) void seg_correct(
    const float* __restrict__ Gbuf, const float* __restrict__ zbuf,
    float* __restrict__ out)
{
    constexpr int NP = Ss / SEG;
    const int bid = (int)blockIdx.x;              // bh*(NP-1) + (p-1)
    const int bh  = bid / (NP - 1);
    const int p   = bid % (NP - 1) + 1;
    const int tid = (int)threadIdx.x;
    const int lane = tid & 63;
    const int w    = tid >> 6;
    const int b = bh >> 5, hh = bh & (Hh - 1);

    __shared__ float SWs[4096];
    __shared__ float zs[SEG * 64];

    const float* sw = Gbuf + ((size_t)bh * NP + p - 1) * 4096;
    const float* zp = zbuf + ((size_t)(bh * NP + p)) * (SEG * 64);
    for (int i = tid; i < 4096; i += 256)
        SWs[i] = sw[i];
    for (int i = tid; i < SEG * 64; i += 256)
        zs[i] = zp[i];
    __syncthreads();

    for (int t = w; t < SEG; t += 4) {
        float a0 = 0.f, a1 = 0.f, a2 = 0.f, a3 = 0.f;
#pragma unroll
        for (int k = 0; k < 64; k += 4) {
            a0 = fmaf(zs[t * 64 + k + 0], SWs[(k + 0) * 64 + lane], a0);
            a1 = fmaf(zs[t * 64 + k + 1], SWs[(k + 1) * 64 + lane], a1);
            a2 = fmaf(zs[t * 64 + k + 2], SWs[(k + 2) * 64 + lane], a2);
            a3 = fmaf(zs[t * 64 + k + 3], SWs[(k + 3) * 64 + lane], a3);
        }
        const int s = p * SEG + t;
        const size_t o = (((size_t)b * Ss + s) * Hh + hh) * Dd + lane;
        out[o] += (a0 + a1) + (a2 + a3);
    }
}

// ---------------------------------------------------------------------------
// Epilogue (unchanged): in-place GroupNorm + correction + gate on d_out.
// ---------------------------------------------------------------------------
__global__ __launch_bounds__(256) void epilogue(
    const float* __restrict__ qp, const float* __restrict__ kp,
    const float* __restrict__ vp, const float* __restrict__ rk,
    const float* __restrict__ gp, const float* __restrict__ sc,
    const float* __restrict__ bi, float* __restrict__ out)
{
    const int lane = (int)(threadIdx.x & 63u);
    const int gid  = (int)blockIdx.x * 4 + (int)(threadIdx.x >> 6);
    const int hh   = gid & (Hh - 1);
    const int bs   = gid >> 5;
    const int b    = bs >> 10;
    const int s    = bs & (Ss - 1);

    const size_t ioff = ((size_t)(b * Hh + hh) * Ss + s) * Dd + lane;
    const float qv = qp[ioff];
    const float kv = kp[ioff];
    const float vv = vp[ioff];
    const float r  = rk[hh * Dd + lane];

    const size_t goff = (size_t)bs * (Hh * Dd) + hh * Dd + lane;
    const float o = out[goff];

    float s1 = o, s2 = o * o, s3 = qv * kv * r;
#pragma unroll
    for (int m = 32; m >= 1; m >>= 1) {
        s1 += __shfl_xor(s1, m, 64);
        s2 += __shfl_xor(s2, m, 64);
        s3 += __shfl_xor(s3, m, 64);
    }
    const float mu  = s1 * (1.f / 64.f);
    const float var = fmaf(-mu, mu, s2 * (1.f / 64.f));
    const float on  = (o - mu) * rsqrtf(var + 1e-5f);

    out[goff] = (fmaf(on, sc[hh * Dd + lane], bi[hh * Dd + lane]) + s3 * vv) * gp[goff];
}

// ---------------------------------------------------------------------------
extern "C" void kernel_launch(void* const* d_in, const int* in_sizes, int n_in,
                              void* d_out, int out_size, void* d_ws, size_t ws_size,
                              hipStream_t stream)
{
    const float* q   = (const float*)d_in[0];
    const float* k   = (const float*)d_in[1];
    const float* v   = (const float*)d_in[2];
    const float* a   = (const float*)d_in[3];
    const float* b   = (const float*)d_in[4];
    const float* gk  = (const float*)d_in[5];
    const float* r_k = (const float*)d_in[6];
    const float* g   = (const float*)d_in[7];
    const float* gns = (const float*)d_in[8];
    const float* gnb = (const float*)d_in[9];
    float* out = (float*)d_out;
    float* ws  = (float*)d_ws;

    const size_t zfl   = (size_t)NBH * Ss * 64;          // z floats (16.78 MB)
    const size_t gm32  = (size_t)NBH * 32 * 4096;        // G or M floats @NP=32
    const size_t gm16  = (size_t)NBH * 16 * 4096;        // G or M floats @NP=16
    const size_t need32 = (2 * gm32 + zfl) * sizeof(float);   // 83.9 MB
    const size_t need16 = (2 * gm16 + zfl) * sizeof(float);   // 50.3 MB

    if (ws_size >= need32) {
        // NP=32: 4096 scan waves -> 16 waves/CU.
        float* G = ws;
        float* M = ws + gm32;
        float* Z = ws + 2 * gm32;
        scan_wave<32, 8><<<dim3(NBH * 32), dim3(128), 0, stream>>>(
            q, k, v, a, b, gk, G, M, Z, out);
        combine<32><<<dim3(NBH * 4), dim3(256), 0, stream>>>(M, M, 32, G);
        seg_correct<32><<<dim3(NBH * 31), dim3(256), 0, stream>>>(G, Z, out);
    } else if (ws_size >= need16) {
        // NP=16 (round-10 proven path).
        float* G = ws;
        float* M = ws + gm16;
        float* Z = ws + 2 * gm16;
        scan_wave<64, 16><<<dim3(NBH * 16), dim3(128), 0, stream>>>(
            q, k, v, a, b, gk, G, M, Z, out);
        combine<16><<<dim3(NBH * 4), dim3(256), 0, stream>>>(M, M, 16, G);
        seg_correct<64><<<dim3(NBH * 15), dim3(256), 0, stream>>>(G, Z, out);
    } else {
        // Minimal-workspace last resort: NP=16 with z parked right after G+M
        // is impossible; reuse NP=16 kernels with G,M in ws and z in the tail
        // of ws (requires 50.3 MB; harness has provided >=64 MiB every round).
        float* G = ws;
        float* M = ws + gm16;
        float* Z = ws + 2 * gm16;
        scan_wave<64, 16><<<dim3(NBH * 16), dim3(128), 0, stream>>>(
            q, k, v, a, b, gk, G, M, Z, out);
        combine<16><<<dim3(NBH * 4), dim3(256), 0, stream>>>(M, M, 16, G);
        seg_correct<64><<<dim3(NBH * 15), dim3(256), 0, stream>>>(G, Z, out);
    }

    epilogue<<<dim3(Bb * Ss * Hh / 4), dim3(256), 0, stream>>>(
        q, k, v, r_k, g, gns, gnb, out);
}

// Round 12
// 234.487 us; speedup vs baseline: 1.2661x; 1.2661x over previous
//
#include <hip/hip_runtime.h>
#include <hip/hip_bf16.h>

constexpr int Bb = 2, Hh = 32, Ss = 1024, Dd = 64;
constexpr int NBH = Bb * Hh;     // 64

// ---------------------------------------------------------------------------
// Phase 1: BARRIER-FREE per-step scan. One 128-thread block per (bh,p):
//   wave 0 (G): h[64] zero-init, input k v^T; per-step o_t = q^T h -> out
//   wave 1 (M): h[64] identity-init, homogeneous; per-step z_t = q^T M -> zbuf
// Full 64-row state in ONE wave's VGPRs; a^T h, update, q^T h all in-register.
// LDS staging per CH-step chunk (2 barriers per chunk), fully unrolled steps.
// __launch_bounds__(128, 2): do NOT constrain the allocator below the h[64]
// state (r11 lesson: (128,4) forced VGPR=64 -> full state spill -> 511 MB of
// scratch traffic). At VGPR~116 the HW still fits 4 waves/SIMD; the grid
// (2048 blocks at NP=32) supplies 16 waves/CU.
// ---------------------------------------------------------------------------
template<int SEG, int CH>
__global__ __launch_bounds__(128, 2) void scan_wave(
    const float* __restrict__ qp, const float* __restrict__ kp,
    const float* __restrict__ vp, const float* __restrict__ ap,
    const float* __restrict__ bp, const float* __restrict__ gkp,
    float* __restrict__ Gbuf, float* __restrict__ Mbuf,
    float* __restrict__ zbuf, float* __restrict__ out)
{
    constexpr int NP = Ss / SEG;
    const int tid  = (int)threadIdx.x;
    const int lane = tid & 63;
    const int wv   = __builtin_amdgcn_readfirstlane(tid >> 6);   // 0=G, 1=M
    const int bid  = (int)blockIdx.x;            // bh*NP + p
    const int p    = bid & (NP - 1);
    const int bh   = bid / NP;
    const int b    = bh >> 5, hh = bh & (Hh - 1);
    const size_t segbase = (size_t)bid * (SEG * Dd);

    __shared__ float la[CH * 64], lb[CH * 64], lw_[CH * 64];
    __shared__ float lq[CH * 64], lk[CH * 64], lv[CH * 64];

    float h[64];
#pragma unroll
    for (int j = 0; j < 64; ++j) h[j] = wv ? ((j == lane) ? 1.f : 0.f) : 0.f;

    for (int c0 = 0; c0 < SEG; c0 += CH) {
        __syncthreads();                          // prior chunk LDS reads done
        {
            const size_t gb = segbase + (size_t)c0 * 64;
            const float4* a4 = (const float4*)(ap + gb);
            const float4* b4 = (const float4*)(bp + gb);
            const float4* g4 = (const float4*)(gkp + gb);
            const float4* q4 = (const float4*)(qp + gb);
            const float4* k4 = (const float4*)(kp + gb);
            const float4* v4 = (const float4*)(vp + gb);
#pragma unroll
            for (int i = tid; i < CH * 16; i += 128) {
                ((float4*)la)[i] = a4[i];
                ((float4*)lb)[i] = b4[i];
                float4 g = g4[i], e;
                e.x = __expf(g.x); e.y = __expf(g.y);
                e.z = __expf(g.z); e.w = __expf(g.w);
                ((float4*)lw_)[i] = e;
                ((float4*)lq)[i] = q4[i];
                ((float4*)lk)[i] = k4[i];
                ((float4*)lv)[i] = v4[i];
            }
        }
        __syncthreads();                          // staging visible

#pragma unroll
        for (int tl = 0; tl < CH; ++tl) {
            const int t = c0 + tl;
            // ---- a^T h : 64 in-register FMAs (broadcast b128 reads of a)
            const float4* ar = (const float4*)(la + tl * 64);
            float s0 = 0.f, s1 = 0.f, s2 = 0.f, s3 = 0.f;
#pragma unroll
            for (int jj = 0; jj < 16; ++jj) {
                const float4 a4 = ar[jj];
                s0 = fmaf(a4.x, h[4*jj+0], s0);
                s1 = fmaf(a4.y, h[4*jj+1], s1);
                s2 = fmaf(a4.z, h[4*jj+2], s2);
                s3 = fmaf(a4.w, h[4*jj+3], s3);
            }
            const float ah = (s0 + s1) + (s2 + s3);

            // ---- state update + q^T h (all in-register)
            const float4* br = (const float4*)(lb  + tl * 64);
            const float4* wr = (const float4*)(lw_ + tl * 64);
            const float4* qr = (const float4*)(lq  + tl * 64);
            float o0 = 0.f, o1 = 0.f, o2 = 0.f, o3 = 0.f;
            if (wv == 0) {                        // G wave
                const float u = lv[tl * 64 + lane];
                const float4* kr = (const float4*)(lk + tl * 64);
#pragma unroll
                for (int jj = 0; jj < 16; ++jj) {
                    const float4 b4 = br[jj], k4 = kr[jj], w4 = wr[jj], q4 = qr[jj];
                    h[4*jj+0] = fmaf(w4.x, h[4*jj+0], fmaf(b4.x, ah, k4.x * u));
                    o0 = fmaf(q4.x, h[4*jj+0], o0);
                    h[4*jj+1] = fmaf(w4.y, h[4*jj+1], fmaf(b4.y, ah, k4.y * u));
                    o1 = fmaf(q4.y, h[4*jj+1], o1);
                    h[4*jj+2] = fmaf(w4.z, h[4*jj+2], fmaf(b4.z, ah, k4.z * u));
                    o2 = fmaf(q4.z, h[4*jj+2], o2);
                    h[4*jj+3] = fmaf(w4.w, h[4*jj+3], fmaf(b4.w, ah, k4.w * u));
                    o3 = fmaf(q4.w, h[4*jj+3], o3);
                }
                const int s = p * SEG + t;
                out[(((size_t)b * Ss + s) * Hh + hh) * Dd + lane] =
                    (o0 + o1) + (o2 + o3);
            } else {                              // M wave
#pragma unroll
                for (int jj = 0; jj < 16; ++jj) {
                    const float4 b4 = br[jj], w4 = wr[jj], q4 = qr[jj];
                    h[4*jj+0] = fmaf(w4.x, h[4*jj+0], b4.x * ah);
                    o0 = fmaf(q4.x, h[4*jj+0], o0);
                    h[4*jj+1] = fmaf(w4.y, h[4*jj+1], b4.y * ah);
                    o1 = fmaf(q4.y, h[4*jj+1], o1);
                    h[4*jj+2] = fmaf(w4.z, h[4*jj+2], b4.z * ah);
                    o2 = fmaf(q4.z, h[4*jj+2], o2);
                    h[4*jj+3] = fmaf(w4.w, h[4*jj+3], b4.w * ah);
                    o3 = fmaf(q4.w, h[4*jj+3], o3);
                }
                zbuf[segbase + (size_t)t * 64 + lane] = (o0 + o1) + (o2 + o3);
            }
        }
    }

    float* dst = (wv == 0) ? Gbuf + (size_t)bid * 4096
                           : Mbuf + (size_t)bid * 4096;
#pragma unroll
    for (int j = 0; j < 64; ++j) dst[j * 64 + lane] = h[j];
}

// ---------------------------------------------------------------------------
// Phase 2 (proven r8-r10): SW_p = M_p * SW_{p-1} + G_p.
// XCD-aware: bh = bid & 63 -> 4 col-blocks of a bh land on the same XCD.
// ---------------------------------------------------------------------------
template<int NP>
__global__ __launch_bounds__(256) void combine(
    const float* __restrict__ Mbuf, float* __restrict__ Gbuf)
{
    const int bh  = (int)blockIdx.x & (NBH - 1);
    const int cb  = (int)blockIdx.x >> 6;
    const int c0  = cb * 16;
    const int tid = (int)threadIdx.x;
    const int cl  = tid & 15;
    const int c   = c0 + cl;
    const int rg  = tid >> 4;            // 0..15
    const int r0  = rg * 4;
    const int xorv = (rg & 1) << 2;

    __shared__ float4 Ml[2][1024];
    __shared__ __align__(16) float swT[16][68];

    {
        const float* G0 = Gbuf + (size_t)bh * NP * 4096;
        for (int i = tid; i < 1024; i += 256)
            swT[i & 15][i >> 4] = G0[(i >> 4) * 64 + c0 + (i & 15)];
    }

    float4 mreg[4];
    if (NP > 1) {
        const float4* Mp = (const float4*)(Mbuf + ((size_t)bh * NP + 1) * 4096);
#pragma unroll
        for (int j = 0; j < 4; ++j) mreg[j] = Mp[j * 256 + tid];
    }
    __syncthreads();
#pragma unroll
    for (int j = 0; j < 4; ++j) {
        const int f = j * 256 + tid;
        Ml[0][f ^ ((f >> 4) & 4)] = mreg[j];
    }
    if (NP > 2) {
        const float4* Mp = (const float4*)(Mbuf + ((size_t)bh * NP + 2) * 4096);
#pragma unroll
        for (int j = 0; j < 4; ++j) mreg[j] = Mp[j * 256 + tid];
    }
    __syncthreads();

    for (int p = 1; p < NP; ++p) {
        const int par = (p - 1) & 1;
        float* Gp = Gbuf + ((size_t)bh * NP + p) * 4096;

        float gacc[4];
#pragma unroll
        for (int r = 0; r < 4; ++r) gacc[r] = Gp[(r0 + r) * 64 + c];

        float accA[4] = {0.f, 0.f, 0.f, 0.f};
        float accB[4] = {0.f, 0.f, 0.f, 0.f};
        const float4* swr = (const float4*)&swT[cl][0];
#pragma unroll
        for (int m4 = 0; m4 < 16; ++m4) {
            const float4 s = swr[m4];
            const int ms = m4 ^ xorv;
#pragma unroll
            for (int r = 0; r < 4; ++r) {
                const float4 m = Ml[par][(r0 + r) * 16 + ms];
                accA[r] = fmaf(m.x, s.x, fmaf(m.y, s.y, accA[r]));
                accB[r] = fmaf(m.z, s.z, fmaf(m.w, s.w, accB[r]));
            }
        }
        __syncthreads();

#pragma unroll
        for (int r = 0; r < 4; ++r) {
            const float val = accA[r] + accB[r] + gacc[r];
            swT[cl][r0 + r] = val;
            Gp[(r0 + r) * 64 + c] = val;
        }
        if (p + 1 < NP) {
#pragma unroll
            for (int j = 0; j < 4; ++j) {
                const int f = j * 256 + tid;
                Ml[par ^ 1][f ^ ((f >> 4) & 4)] = mreg[j];
            }
        }
        if (p + 2 < NP) {
            const float4* Mp = (const float4*)(Mbuf + ((size_t)bh * NP + p + 2) * 4096);
#pragma unroll
            for (int j = 0; j < 4; ++j) mreg[j] = Mp[j * 256 + tid];
        }
        __syncthreads();
    }
}

// ---------------------------------------------------------------------------
// Phase 3 (proven r8-r10): out[t] += z_t^T SW_{p-1}.
// ---------------------------------------------------------------------------
template<int SEG>
__global__ __launch_bounds__(256) void seg_correct(
    const float* __restrict__ Gbuf, const float* __restrict__ zbuf,
    float* __restrict__ out)
{
    constexpr int NP = Ss / SEG;
    const int bid = (int)blockIdx.x;              // bh*(NP-1) + (p-1)
    const int bh  = bid / (NP - 1);
    const int p   = bid % (NP - 1) + 1;
    const int tid = (int)threadIdx.x;
    const int lane = tid & 63;
    const int w    = tid >> 6;
    const int b = bh >> 5, hh = bh & (Hh - 1);

    __shared__ float SWs[4096];
    __shared__ float zs[SEG * 64];

    const float* sw = Gbuf + ((size_t)bh * NP + p - 1) * 4096;
    const float* zp = zbuf + ((size_t)(bh * NP + p)) * (SEG * 64);
    for (int i = tid; i < 4096; i += 256)
        SWs[i] = sw[i];
    for (int i = tid; i < SEG * 64; i += 256)
        zs[i] = zp[i];
    __syncthreads();

    for (int t = w; t < SEG; t += 4) {
        float a0 = 0.f, a1 = 0.f, a2 = 0.f, a3 = 0.f;
#pragma unroll
        for (int k = 0; k < 64; k += 4) {
            a0 = fmaf(zs[t * 64 + k + 0], SWs[(k + 0) * 64 + lane], a0);
            a1 = fmaf(zs[t * 64 + k + 1], SWs[(k + 1) * 64 + lane], a1);
            a2 = fmaf(zs[t * 64 + k + 2], SWs[(k + 2) * 64 + lane], a2);
            a3 = fmaf(zs[t * 64 + k + 3], SWs[(k + 3) * 64 + lane], a3);
        }
        const int s = p * SEG + t;
        const size_t o = (((size_t)b * Ss + s) * Hh + hh) * Dd + lane;
        out[o] += (a0 + a1) + (a2 + a3);
    }
}

// ---------------------------------------------------------------------------
// Epilogue (unchanged): in-place GroupNorm + correction + gate on d_out.
// ---------------------------------------------------------------------------
__global__ __launch_bounds__(256) void epilogue(
    const float* __restrict__ qp, const float* __restrict__ kp,
    const float* __restrict__ vp, const float* __restrict__ rk,
    const float* __restrict__ gp, const float* __restrict__ sc,
    const float* __restrict__ bi, float* __restrict__ out)
{
    const int lane = (int)(threadIdx.x & 63u);
    const int gid  = (int)blockIdx.x * 4 + (int)(threadIdx.x >> 6);
    const int hh   = gid & (Hh - 1);
    const int bs   = gid >> 5;
    const int b    = bs >> 10;
    const int s    = bs & (Ss - 1);

    const size_t ioff = ((size_t)(b * Hh + hh) * Ss + s) * Dd + lane;
    const float qv = qp[ioff];
    const float kv = kp[ioff];
    const float vv = vp[ioff];
    const float r  = rk[hh * Dd + lane];

    const size_t goff = (size_t)bs * (Hh * Dd) + hh * Dd + lane;
    const float o = out[goff];

    float s1 = o, s2 = o * o, s3 = qv * kv * r;
#pragma unroll
    for (int m = 32; m >= 1; m >>= 1) {
        s1 += __shfl_xor(s1, m, 64);
        s2 += __shfl_xor(s2, m, 64);
        s3 += __shfl_xor(s3, m, 64);
    }
    const float mu  = s1 * (1.f / 64.f);
    const float var = fmaf(-mu, mu, s2 * (1.f / 64.f));
    const float on  = (o - mu) * rsqrtf(var + 1e-5f);

    out[goff] = (fmaf(on, sc[hh * Dd + lane], bi[hh * Dd + lane]) + s3 * vv) * gp[goff];
}

// ---------------------------------------------------------------------------
extern "C" void kernel_launch(void* const* d_in, const int* in_sizes, int n_in,
                              void* d_out, int out_size, void* d_ws, size_t ws_size,
                              hipStream_t stream)
{
    const float* q   = (const float*)d_in[0];
    const float* k   = (const float*)d_in[1];
    const float* v   = (const float*)d_in[2];
    const float* a   = (const float*)d_in[3];
    const float* b   = (const float*)d_in[4];
    const float* gk  = (const float*)d_in[5];
    const float* r_k = (const float*)d_in[6];
    const float* g   = (const float*)d_in[7];
    const float* gns = (const float*)d_in[8];
    const float* gnb = (const float*)d_in[9];
    float* out = (float*)d_out;
    float* ws  = (float*)d_ws;

    const size_t zfl   = (size_t)NBH * Ss * 64;          // z floats (16.78 MB)
    const size_t gm32  = (size_t)NBH * 32 * 4096;        // G or M floats @NP=32
    const size_t gm16  = (size_t)NBH * 16 * 4096;        // G or M floats @NP=16
    const size_t need32 = (2 * gm32 + zfl) * sizeof(float);   // 83.9 MB
    const size_t need16 = (2 * gm16 + zfl) * sizeof(float);   // 50.3 MB

    if (ws_size >= need32) {
        // NP=32: 2048 blocks x 2 waves -> 16 waves/CU (grid-supplied).
        float* G = ws;
        float* M = ws + gm32;
        float* Z = ws + 2 * gm32;
        scan_wave<32, 8><<<dim3(NBH * 32), dim3(128), 0, stream>>>(
            q, k, v, a, b, gk, G, M, Z, out);
        combine<32><<<dim3(NBH * 4), dim3(256), 0, stream>>>(M, G);
        seg_correct<32><<<dim3(NBH * 31), dim3(256), 0, stream>>>(G, Z, out);
    } else {
        // NP=16 (round-10 proven path, 50.3 MB).
        float* G = ws;
        float* M = ws + gm16;
        float* Z = ws + 2 * gm16;
        scan_wave<64, 16><<<dim3(NBH * 16), dim3(128), 0, stream>>>(
            q, k, v, a, b, gk, G, M, Z, out);
        combine<16><<<dim3(NBH * 4), dim3(256), 0, stream>>>(M, G);
        seg_correct<64><<<dim3(NBH * 15), dim3(256), 0, stream>>>(G, Z, out);
    }

    epilogue<<<dim3(Bb * Ss * Hh / 4), dim3(256), 0, stream>>>(
        q, k, v, r_k, g, gns, gnb, out);
}

// Round 13
// 195.074 us; speedup vs baseline: 1.5218x; 1.2020x over previous
//
#include <hip/hip_runtime.h>
#include <hip/hip_bf16.h>

constexpr int Bb = 2, Hh = 32, Ss = 1024, Dd = 64;
constexpr int NBH = Bb * Hh;     // 64

// ---------------------------------------------------------------------------
// Phase 1: MERGED G+M scan. ONE 64-thread wave per (bh,p) segment holds BOTH
// states in VGPRs: h[64] (zero-init, k v^T input) and m[64] (identity-init,
// homogeneous). Every broadcast ds_read of a/b/w/q feeds BOTH updates ->
// halves the per-CU LDS issue traffic (the r10/r12 bottleneck).
//   o_t = q^T h -> out ;  z_t = q^T m -> zbuf ;  final h -> G, m -> M.
// No per-step barriers (single wave). LDS staging per CH-step chunk.
// __launch_bounds__(64,2): allocator cap 256 VGPR -- state is ~190, no spill.
// ---------------------------------------------------------------------------
template<int SEG, int CH>
__global__ __launch_bounds__(64, 2) void scan_gm(
    const float* __restrict__ qp, const float* __restrict__ kp,
    const float* __restrict__ vp, const float* __restrict__ ap,
    const float* __restrict__ bp, const float* __restrict__ gkp,
    float* __restrict__ Gbuf, float* __restrict__ Mbuf,
    float* __restrict__ zbuf, float* __restrict__ out)
{
    constexpr int NP = Ss / SEG;
    const int lane = (int)threadIdx.x;           // 0..63
    const int bid  = (int)blockIdx.x;            // bh*NP + p
    const int p    = bid & (NP - 1);
    const int bh   = bid / NP;
    const int b    = bh >> 5, hh = bh & (Hh - 1);
    const size_t segbase = (size_t)bid * (SEG * Dd);

    __shared__ float la[CH * 64], lb[CH * 64], lw_[CH * 64];
    __shared__ float lq[CH * 64], lk[CH * 64], lv[CH * 64];

    float h[64], m[64];
#pragma unroll
    for (int j = 0; j < 64; ++j) {
        h[j] = 0.f;
        m[j] = (j == lane) ? 1.f : 0.f;
    }

    for (int c0 = 0; c0 < SEG; c0 += CH) {
        __syncthreads();                          // prior chunk LDS reads done
        {
            const size_t gb = segbase + (size_t)c0 * 64;
            const float4* a4 = (const float4*)(ap + gb);
            const float4* b4 = (const float4*)(bp + gb);
            const float4* g4 = (const float4*)(gkp + gb);
            const float4* q4 = (const float4*)(qp + gb);
            const float4* k4 = (const float4*)(kp + gb);
            const float4* v4 = (const float4*)(vp + gb);
#pragma unroll
            for (int i = lane; i < CH * 16; i += 64) {
                ((float4*)la)[i] = a4[i];
                ((float4*)lb)[i] = b4[i];
                float4 g = g4[i], e;
                e.x = __expf(g.x); e.y = __expf(g.y);
                e.z = __expf(g.z); e.w = __expf(g.w);
                ((float4*)lw_)[i] = e;
                ((float4*)lq)[i] = q4[i];
                ((float4*)lk)[i] = k4[i];
                ((float4*)lv)[i] = v4[i];
            }
        }
        __syncthreads();                          // staging visible

#pragma unroll
        for (int tl = 0; tl < CH; ++tl) {
            const int t = c0 + tl;
            // ---- ah = a^T h and am = a^T m (one a-read feeds both)
            const float4* ar = (const float4*)(la + tl * 64);
            float s0 = 0.f, s1 = 0.f, s2 = 0.f, s3 = 0.f;
            float r0 = 0.f, r1 = 0.f, r2 = 0.f, r3 = 0.f;
#pragma unroll
            for (int jj = 0; jj < 16; ++jj) {
                const float4 a4 = ar[jj];
                s0 = fmaf(a4.x, h[4*jj+0], s0);
                r0 = fmaf(a4.x, m[4*jj+0], r0);
                s1 = fmaf(a4.y, h[4*jj+1], s1);
                r1 = fmaf(a4.y, m[4*jj+1], r1);
                s2 = fmaf(a4.z, h[4*jj+2], s2);
                r2 = fmaf(a4.z, m[4*jj+2], r2);
                s3 = fmaf(a4.w, h[4*jj+3], s3);
                r3 = fmaf(a4.w, m[4*jj+3], r3);
            }
            const float ah = (s0 + s1) + (s2 + s3);
            const float am = (r0 + r1) + (r2 + r3);

            // ---- both state updates + both q-dots (b/w/q reads shared)
            const float u = lv[tl * 64 + lane];
            const float4* br = (const float4*)(lb  + tl * 64);
            const float4* wr = (const float4*)(lw_ + tl * 64);
            const float4* qr = (const float4*)(lq  + tl * 64);
            const float4* kr = (const float4*)(lk  + tl * 64);
            float o0 = 0.f, o1 = 0.f, o2 = 0.f, o3 = 0.f;
            float z0 = 0.f, z1 = 0.f, z2 = 0.f, z3 = 0.f;
#pragma unroll
            for (int jj = 0; jj < 16; ++jj) {
                const float4 b4 = br[jj], k4 = kr[jj], w4 = wr[jj], q4 = qr[jj];
                h[4*jj+0] = fmaf(w4.x, h[4*jj+0], fmaf(b4.x, ah, k4.x * u));
                m[4*jj+0] = fmaf(w4.x, m[4*jj+0], b4.x * am);
                o0 = fmaf(q4.x, h[4*jj+0], o0);
                z0 = fmaf(q4.x, m[4*jj+0], z0);
                h[4*jj+1] = fmaf(w4.y, h[4*jj+1], fmaf(b4.y, ah, k4.y * u));
                m[4*jj+1] = fmaf(w4.y, m[4*jj+1], b4.y * am);
                o1 = fmaf(q4.y, h[4*jj+1], o1);
                z1 = fmaf(q4.y, m[4*jj+1], z1);
                h[4*jj+2] = fmaf(w4.z, h[4*jj+2], fmaf(b4.z, ah, k4.z * u));
                m[4*jj+2] = fmaf(w4.z, m[4*jj+2], b4.z * am);
                o2 = fmaf(q4.z, h[4*jj+2], o2);
                z2 = fmaf(q4.z, m[4*jj+2], z2);
                h[4*jj+3] = fmaf(w4.w, h[4*jj+3], fmaf(b4.w, ah, k4.w * u));
                m[4*jj+3] = fmaf(w4.w, m[4*jj+3], b4.w * am);
                o3 = fmaf(q4.w, h[4*jj+3], o3);
                z3 = fmaf(q4.w, m[4*jj+3], z3);
            }
            const int s = p * SEG + t;
            out[(((size_t)b * Ss + s) * Hh + hh) * Dd + lane] =
                (o0 + o1) + (o2 + o3);
            zbuf[segbase + (size_t)t * 64 + lane] = (z0 + z1) + (z2 + z3);
        }
    }

    float* gd = Gbuf + (size_t)bid * 4096;
    float* md = Mbuf + (size_t)bid * 4096;
#pragma unroll
    for (int j = 0; j < 64; ++j) {
        gd[j * 64 + lane] = h[j];
        md[j * 64 + lane] = m[j];
    }
}

// ---------------------------------------------------------------------------
// Phase 2 (proven r8-r12): SW_p = M_p * SW_{p-1} + G_p.
// XCD-aware: bh = bid & 63 -> 4 col-blocks of a bh land on the same XCD.
// ---------------------------------------------------------------------------
template<int NP>
__global__ __launch_bounds__(256) void combine(
    const float* __restrict__ Mbuf, float* __restrict__ Gbuf)
{
    const int bh  = (int)blockIdx.x & (NBH - 1);
    const int cb  = (int)blockIdx.x >> 6;
    const int c0  = cb * 16;
    const int tid = (int)threadIdx.x;
    const int cl  = tid & 15;
    const int c   = c0 + cl;
    const int rg  = tid >> 4;            // 0..15
    const int r0  = rg * 4;
    const int xorv = (rg & 1) << 2;

    __shared__ float4 Ml[2][1024];
    __shared__ __align__(16) float swT[16][68];

    {
        const float* G0 = Gbuf + (size_t)bh * NP * 4096;
        for (int i = tid; i < 1024; i += 256)
            swT[i & 15][i >> 4] = G0[(i >> 4) * 64 + c0 + (i & 15)];
    }

    float4 mreg[4];
    if (NP > 1) {
        const float4* Mp = (const float4*)(Mbuf + ((size_t)bh * NP + 1) * 4096);
#pragma unroll
        for (int j = 0; j < 4; ++j) mreg[j] = Mp[j * 256 + tid];
    }
    __syncthreads();
#pragma unroll
    for (int j = 0; j < 4; ++j) {
        const int f = j * 256 + tid;
        Ml[0][f ^ ((f >> 4) & 4)] = mreg[j];
    }
    if (NP > 2) {
        const float4* Mp = (const float4*)(Mbuf + ((size_t)bh * NP + 2) * 4096);
#pragma unroll
        for (int j = 0; j < 4; ++j) mreg[j] = Mp[j * 256 + tid];
    }
    __syncthreads();

    for (int p = 1; p < NP; ++p) {
        const int par = (p - 1) & 1;
        float* Gp = Gbuf + ((size_t)bh * NP + p) * 4096;

        float gacc[4];
#pragma unroll
        for (int r = 0; r < 4; ++r) gacc[r] = Gp[(r0 + r) * 64 + c];

        float accA[4] = {0.f, 0.f, 0.f, 0.f};
        float accB[4] = {0.f, 0.f, 0.f, 0.f};
        const float4* swr = (const float4*)&swT[cl][0];
#pragma unroll
        for (int m4 = 0; m4 < 16; ++m4) {
            const float4 s = swr[m4];
            const int ms = m4 ^ xorv;
#pragma unroll
            for (int r = 0; r < 4; ++r) {
                const float4 m = Ml[par][(r0 + r) * 16 + ms];
                accA[r] = fmaf(m.x, s.x, fmaf(m.y, s.y, accA[r]));
                accB[r] = fmaf(m.z, s.z, fmaf(m.w, s.w, accB[r]));
            }
        }
        __syncthreads();

#pragma unroll
        for (int r = 0; r < 4; ++r) {
            const float val = accA[r] + accB[r] + gacc[r];
            swT[cl][r0 + r] = val;
            Gp[(r0 + r) * 64 + c] = val;
        }
        if (p + 1 < NP) {
#pragma unroll
            for (int j = 0; j < 4; ++j) {
                const int f = j * 256 + tid;
                Ml[par ^ 1][f ^ ((f >> 4) & 4)] = mreg[j];
            }
        }
        if (p + 2 < NP) {
            const float4* Mp = (const float4*)(Mbuf + ((size_t)bh * NP + p + 2) * 4096);
#pragma unroll
            for (int j = 0; j < 4; ++j) mreg[j] = Mp[j * 256 + tid];
        }
        __syncthreads();
    }
}

// ---------------------------------------------------------------------------
// Phase 3 (proven r8-r12): out[t] += z_t^T SW_{p-1}.
// ---------------------------------------------------------------------------
template<int SEG>
__global__ __launch_bounds__(256) void seg_correct(
    const float* __restrict__ Gbuf, const float* __restrict__ zbuf,
    float* __restrict__ out)
{
    constexpr int NP = Ss / SEG;
    const int bid = (int)blockIdx.x;              // bh*(NP-1) + (p-1)
    const int bh  = bid / (NP - 1);
    const int p   = bid % (NP - 1) + 1;
    const int tid = (int)threadIdx.x;
    const int lane = tid & 63;
    const int w    = tid >> 6;
    const int b = bh >> 5, hh = bh & (Hh - 1);

    __shared__ float SWs[4096];
    __shared__ float zs[SEG * 64];

    const float* sw = Gbuf + ((size_t)bh * NP + p - 1) * 4096;
    const float* zp = zbuf + ((size_t)(bh * NP + p)) * (SEG * 64);
    for (int i = tid; i < 4096; i += 256)
        SWs[i] = sw[i];
    for (int i = tid; i < SEG * 64; i += 256)
        zs[i] = zp[i];
    __syncthreads();

    for (int t = w; t < SEG; t += 4) {
        float a0 = 0.f, a1 = 0.f, a2 = 0.f, a3 = 0.f;
#pragma unroll
        for (int k = 0; k < 64; k += 4) {
            a0 = fmaf(zs[t * 64 + k + 0], SWs[(k + 0) * 64 + lane], a0);
            a1 = fmaf(zs[t * 64 + k + 1], SWs[(k + 1) * 64 + lane], a1);
            a2 = fmaf(zs[t * 64 + k + 2], SWs[(k + 2) * 64 + lane], a2);
            a3 = fmaf(zs[t * 64 + k + 3], SWs[(k + 3) * 64 + lane], a3);
        }
        const int s = p * SEG + t;
        const size_t o = (((size_t)b * Ss + s) * Hh + hh) * Dd + lane;
        out[o] += (a0 + a1) + (a2 + a3);
    }
}

// ---------------------------------------------------------------------------
// Epilogue (unchanged): in-place GroupNorm + correction + gate on d_out.
// ---------------------------------------------------------------------------
__global__ __launch_bounds__(256) void epilogue(
    const float* __restrict__ qp, const float* __restrict__ kp,
    const float* __restrict__ vp, const float* __restrict__ rk,
    const float* __restrict__ gp, const float* __restrict__ sc,
    const float* __restrict__ bi, float* __restrict__ out)
{
    const int lane = (int)(threadIdx.x & 63u);
    const int gid  = (int)blockIdx.x * 4 + (int)(threadIdx.x >> 6);
    const int hh   = gid & (Hh - 1);
    const int bs   = gid >> 5;
    const int b    = bs >> 10;
    const int s    = bs & (Ss - 1);

    const size_t ioff = ((size_t)(b * Hh + hh) * Ss + s) * Dd + lane;
    const float qv = qp[ioff];
    const float kv = kp[ioff];
    const float vv = vp[ioff];
    const float r  = rk[hh * Dd + lane];

    const size_t goff = (size_t)bs * (Hh * Dd) + hh * Dd + lane;
    const float o = out[goff];

    float s1 = o, s2 = o * o, s3 = qv * kv * r;
#pragma unroll
    for (int m = 32; m >= 1; m >>= 1) {
        s1 += __shfl_xor(s1, m, 64);
        s2 += __shfl_xor(s2, m, 64);
        s3 += __shfl_xor(s3, m, 64);
    }
    const float mu  = s1 * (1.f / 64.f);
    const float var = fmaf(-mu, mu, s2 * (1.f / 64.f));
    const float on  = (o - mu) * rsqrtf(var + 1e-5f);

    out[goff] = (fmaf(on, sc[hh * Dd + lane], bi[hh * Dd + lane]) + s3 * vv) * gp[goff];
}

// ---------------------------------------------------------------------------
extern "C" void kernel_launch(void* const* d_in, const int* in_sizes, int n_in,
                              void* d_out, int out_size, void* d_ws, size_t ws_size,
                              hipStream_t stream)
{
    const float* q   = (const float*)d_in[0];
    const float* k   = (const float*)d_in[1];
    const float* v   = (const float*)d_in[2];
    const float* a   = (const float*)d_in[3];
    const float* b   = (const float*)d_in[4];
    const float* gk  = (const float*)d_in[5];
    const float* r_k = (const float*)d_in[6];
    const float* g   = (const float*)d_in[7];
    const float* gns = (const float*)d_in[8];
    const float* gnb = (const float*)d_in[9];
    float* out = (float*)d_out;
    float* ws  = (float*)d_ws;

    const size_t zfl   = (size_t)NBH * Ss * 64;          // z floats (16.78 MB)
    const size_t gm32  = (size_t)NBH * 32 * 4096;        // G or M floats @NP=32
    const size_t gm16  = (size_t)NBH * 16 * 4096;        // G or M floats @NP=16
    const size_t need32 = (2 * gm32 + zfl) * sizeof(float);   // 83.9 MB
    const size_t need16 = (2 * gm16 + zfl) * sizeof(float);   // 50.3 MB

    if (ws_size >= need32) {
        // NP=32: 2048 single-wave blocks -> 8 waves/CU (= the 2/SIMD VGPR cap).
        float* G = ws;
        float* M = ws + gm32;
        float* Z = ws + 2 * gm32;
        scan_gm<32, 8><<<dim3(NBH * 32), dim3(64), 0, stream>>>(
            q, k, v, a, b, gk, G, M, Z, out);
        combine<32><<<dim3(NBH * 4), dim3(256), 0, stream>>>(M, G);
        seg_correct<32><<<dim3(NBH * 31), dim3(256), 0, stream>>>(G, Z, out);
    } else {
        // NP=16 fallback (50.3 MB).
        float* G = ws;
        float* M = ws + gm16;
        float* Z = ws + 2 * gm16;
        scan_gm<64, 16><<<dim3(NBH * 16), dim3(64), 0, stream>>>(
            q, k, v, a, b, gk, G, M, Z, out);
        combine<16><<<dim3(NBH * 4), dim3(256), 0, stream>>>(M, G);
        seg_correct<64><<<dim3(NBH * 15), dim3(256), 0, stream>>>(G, Z, out);
    }

    epilogue<<<dim3(Bb * Ss * Hh / 4), dim3(256), 0, stream>>>(
        q, k, v, r_k, g, gns, gnb, out);
}